// Round 2
// baseline (2150.389 us; speedup 1.0000x reference)
//
#include <hip/hip_runtime.h>
#include <hip/hip_bf16.h>
#include <cstdint>
#include <cstddef>
#include <type_traits>

// Problem constants
#define BATCH 8
#define SEQN 4096
#define DIM 1024
#define KSLOT 128
#define MROWS (BATCH * SEQN)   // 32768
#define LN_EPS 1e-5f

typedef __hip_bfloat16 bf16;

// ---------- helpers ----------
__device__ __forceinline__ float bf2f(unsigned short u) {
    return __uint_as_float(((unsigned int)u) << 16);
}
__device__ __forceinline__ unsigned short f2bf(float f) {
    unsigned int u = __float_as_uint(f);
    unsigned int r = (u + 0x7fffu + ((u >> 16) & 1u)) >> 16;  // RNE
    return (unsigned short)r;
}
__device__ __forceinline__ float waveReduceSum(float v) {
    #pragma unroll
    for (int off = 32; off > 0; off >>= 1) v += __shfl_down(v, off, 64);
    return v;
}
// typed 4-element loads/stores (convert to/from fp32)
__device__ __forceinline__ void load4(const float* p, float* o) {
    float4 v = *reinterpret_cast<const float4*>(p);
    o[0] = v.x; o[1] = v.y; o[2] = v.z; o[3] = v.w;
}
__device__ __forceinline__ void load4(const bf16* p, float* o) {
    ushort4 v = *reinterpret_cast<const ushort4*>(p);
    o[0] = bf2f(v.x); o[1] = bf2f(v.y); o[2] = bf2f(v.z); o[3] = bf2f(v.w);
}
__device__ __forceinline__ void store4(float* p, const float* o) {
    float4 v; v.x = o[0]; v.y = o[1]; v.z = o[2]; v.w = o[3];
    *reinterpret_cast<float4*>(p) = v;
}
__device__ __forceinline__ void store4(bf16* p, const float* o) {
    ushort4 v; v.x = f2bf(o[0]); v.y = f2bf(o[1]); v.z = f2bf(o[2]); v.w = f2bf(o[3]);
    *reinterpret_cast<ushort4*>(p) = v;
}

// ---------- kernel 1: input LayerNorm (fp32 in -> bf16 out) ----------
__global__ __launch_bounds__(256) void ln_in_kernel(
    const float* __restrict__ x, const float* __restrict__ g,
    const float* __restrict__ b, bf16* __restrict__ out)
{
    int r = blockIdx.x;
    int t = threadIdx.x;
    float v[4];
    load4(x + (size_t)r * DIM + t * 4, v);
    float sum = v[0] + v[1] + v[2] + v[3];
    float sq  = v[0]*v[0] + v[1]*v[1] + v[2]*v[2] + v[3]*v[3];
    sum = waveReduceSum(sum);
    sq  = waveReduceSum(sq);
    __shared__ float sA[4], sB[4];
    __shared__ float mean_s, rstd_s;
    int w = t >> 6;
    if ((t & 63) == 0) { sA[w] = sum; sB[w] = sq; }
    __syncthreads();
    if (t == 0) {
        float S = sA[0] + sA[1] + sA[2] + sA[3];
        float Q = sB[0] + sB[1] + sB[2] + sB[3];
        float mean = S * (1.0f / DIM);
        float var = Q * (1.0f / DIM) - mean * mean;
        mean_s = mean;
        rstd_s = rsqrtf(fmaxf(var, 0.0f) + LN_EPS);
    }
    __syncthreads();
    float mean = mean_s, rstd = rstd_s;
    float gv[4], bv[4], o[4];
    load4(g + t * 4, gv);
    load4(b + t * 4, bv);
    #pragma unroll
    for (int j = 0; j < 4; j++) o[j] = (v[j] - mean) * rstd * gv[j] + bv[j];
    store4(out + (size_t)r * DIM + t * 4, o);
}

// ---------- generic NT GEMM: C[m,e] = sum_d A[m,d] * W[e,d] (+bias[e]) ----------
// A: M x Kin (AT, row-major), W: Nout x Kin (fp32, row-major), C: OT
// 64x64 tile, BK=16, 256 threads, 4x4 microtile, fp32 accumulate.
template <typename AT, typename OT, bool HAS_BIAS>
__global__ __launch_bounds__(256) void gemm_nt(
    const AT* __restrict__ A, const float* __restrict__ W,
    const float* __restrict__ bias, OT* __restrict__ C,
    int M, int Nout, int Kin)
{
    __shared__ float As[16][68];
    __shared__ float Ws[16][68];
    int tid = threadIdx.x;
    int tx = tid & 15, ty = tid >> 4;
    int m0 = blockIdx.x * 64, e0 = blockIdx.y * 64;
    int lr = tid >> 2;          // 0..63 tile row for loading
    int lk = (tid & 3) * 4;     // 0,4,8,12 k-offset for loading
    const AT* aBase = A + (size_t)(m0 + lr) * Kin + lk;
    const float* wBase = W + (size_t)(e0 + lr) * Kin + lk;
    float acc[4][4] = {};
    for (int kt = 0; kt < Kin; kt += 16) {
        float av[4], wv[4];
        load4(aBase + kt, av);
        load4(wBase + kt, wv);
        #pragma unroll
        for (int j = 0; j < 4; j++) {
            As[lk + j][lr] = av[j];
            Ws[lk + j][lr] = wv[j];
        }
        __syncthreads();
        #pragma unroll
        for (int kk = 0; kk < 16; kk++) {
            float a0 = As[kk][ty * 4 + 0];
            float a1 = As[kk][ty * 4 + 1];
            float a2 = As[kk][ty * 4 + 2];
            float a3 = As[kk][ty * 4 + 3];
            float b0 = Ws[kk][tx * 4 + 0];
            float b1 = Ws[kk][tx * 4 + 1];
            float b2 = Ws[kk][tx * 4 + 2];
            float b3 = Ws[kk][tx * 4 + 3];
            acc[0][0] += a0 * b0; acc[0][1] += a0 * b1; acc[0][2] += a0 * b2; acc[0][3] += a0 * b3;
            acc[1][0] += a1 * b0; acc[1][1] += a1 * b1; acc[1][2] += a1 * b2; acc[1][3] += a1 * b3;
            acc[2][0] += a2 * b0; acc[2][1] += a2 * b1; acc[2][2] += a2 * b2; acc[2][3] += a2 * b3;
            acc[3][0] += a3 * b0; acc[3][1] += a3 * b1; acc[3][2] += a3 * b2; acc[3][3] += a3 * b3;
        }
        __syncthreads();
    }
    float bv[4] = {0.f, 0.f, 0.f, 0.f};
    if (HAS_BIAS) {
        #pragma unroll
        for (int j = 0; j < 4; j++) bv[j] = bias[e0 + tx * 4 + j];
    }
    #pragma unroll
    for (int i = 0; i < 4; i++) {
        int m = m0 + ty * 4 + i;
        float o[4];
        #pragma unroll
        for (int j = 0; j < 4; j++) o[j] = acc[i][j] + bv[j];
        store4(C + (size_t)m * Nout + e0 + tx * 4, o);
    }
}

// ---------- softmax over N (axis=1): stage 1, partial online max/sum ----------
// grid (K/64, 16, B), block (64,4). Each block: 64 cols x 256 positions.
__global__ __launch_bounds__(256) void smax_part_kernel(
    const float* __restrict__ logits, float* __restrict__ pm, float* __restrict__ ps)
{
    int kb = blockIdx.x, nb = blockIdx.y, b = blockIdx.z;
    int tx = threadIdx.x, ty = threadIdx.y;
    int k = kb * 64 + tx;
    const float* base = logits + ((size_t)b * SEQN) * KSLOT + k;
    int n0 = nb * 256 + ty * 64;
    float m = -1e30f, s = 0.0f;
    for (int j = 0; j < 64; j++) {
        float v = base[(size_t)(n0 + j) * KSLOT];
        if (v > m) { s = s * __expf(m - v) + 1.0f; m = v; }
        else       { s += __expf(v - m); }
    }
    __shared__ float lm[4][64], ls[4][64];
    lm[ty][tx] = m; ls[ty][tx] = s;
    __syncthreads();
    if (ty == 0) {
        #pragma unroll
        for (int q = 1; q < 4; q++) {
            float m2 = lm[q][tx], s2 = ls[q][tx];
            float nm = fmaxf(m, m2);
            s = s * __expf(m - nm) + s2 * __expf(m2 - nm);
            m = nm;
        }
        int col = b * KSLOT + k;
        pm[col * 16 + nb] = m;
        ps[col * 16 + nb] = s;
    }
}

// ---------- softmax stage 2: combine 16 partials per column ----------
__global__ __launch_bounds__(256) void smax_comb_kernel(
    const float* __restrict__ pm, const float* __restrict__ ps,
    float* __restrict__ cm, float* __restrict__ cs)
{
    int c = blockIdx.x * 256 + threadIdx.x;  // 0..1023 = b*K+k
    float m = -1e30f, s = 0.0f;
    #pragma unroll
    for (int nb = 0; nb < 16; nb++) {
        float m2 = pm[c * 16 + nb], s2 = ps[c * 16 + nb];
        float nm = fmaxf(m, m2);
        s = s * __expf(m - nm) + s2 * __expf(m2 - nm);
        m = nm;
    }
    cm[c] = m;
    cs[c] = s;
}

// ---------- softmax apply + L1 norm over K, write bf16 ----------
// grid M blocks, 128 threads (one per k).
__global__ __launch_bounds__(128) void l1_kernel(
    const float* __restrict__ logits, const float* __restrict__ cm,
    const float* __restrict__ cs, bf16* __restrict__ aout)
{
    int r = blockIdx.x;
    int b = r >> 12;            // r / SEQN
    int k = threadIdx.x;
    int col = b * KSLOT + k;
    float e = __expf(logits[(size_t)r * KSLOT + k] - cm[col]) / cs[col];
    float t = waveReduceSum(e);
    __shared__ float sh[2];
    __shared__ float tot_s;
    if ((k & 63) == 0) sh[k >> 6] = t;
    __syncthreads();
    if (k == 0) tot_s = sh[0] + sh[1];
    __syncthreads();
    float o = e / (1e-9f + tot_s);
    ((unsigned short*)aout)[(size_t)r * KSLOT + k] = f2bf(o);
}

// ---------- final: out = relu(LN(h3)*g+b + x), in-place fp32 on h ----------
__global__ __launch_bounds__(256) void final_kernel(
    float* __restrict__ h, const float* __restrict__ x,
    const float* __restrict__ g, const float* __restrict__ b)
{
    int r = blockIdx.x;
    int t = threadIdx.x;
    float v[4];
    load4(h + (size_t)r * DIM + t * 4, v);
    float sum = v[0] + v[1] + v[2] + v[3];
    float sq  = v[0]*v[0] + v[1]*v[1] + v[2]*v[2] + v[3]*v[3];
    sum = waveReduceSum(sum);
    sq  = waveReduceSum(sq);
    __shared__ float sA[4], sB[4];
    __shared__ float mean_s, rstd_s;
    int w = t >> 6;
    if ((t & 63) == 0) { sA[w] = sum; sB[w] = sq; }
    __syncthreads();
    if (t == 0) {
        float S = sA[0] + sA[1] + sA[2] + sA[3];
        float Q = sB[0] + sB[1] + sB[2] + sB[3];
        float mean = S * (1.0f / DIM);
        float var = Q * (1.0f / DIM) - mean * mean;
        mean_s = mean;
        rstd_s = rsqrtf(fmaxf(var, 0.0f) + LN_EPS);
    }
    __syncthreads();
    float mean = mean_s, rstd = rstd_s;
    float gv[4], bv[4], xv[4], o[4];
    load4(g + t * 4, gv);
    load4(b + t * 4, bv);
    load4(x + (size_t)r * DIM + t * 4, xv);
    #pragma unroll
    for (int j = 0; j < 4; j++) {
        float z = (v[j] - mean) * rstd * gv[j] + bv[j] + xv[j];
        o[j] = fmaxf(z, 0.0f);
    }
    store4(h + (size_t)r * DIM + t * 4, o);
}

extern "C" void kernel_launch(void* const* d_in, const int* in_sizes, int n_in,
                              void* d_out, int out_size, void* d_ws, size_t ws_size,
                              hipStream_t stream)
{
    const float* x     = (const float*)d_in[0];
    const float* ln_g  = (const float*)d_in[1];
    const float* ln_b  = (const float*)d_in[2];
    const float* w_in  = (const float*)d_in[3];
    const float* b_in  = (const float*)d_in[4];
    const float* w0    = (const float*)d_in[5];
    const float* w1    = (const float*)d_in[6];
    const float* w_out = (const float*)d_in[7];
    const float* oln_g = (const float*)d_in[8];
    const float* oln_b = (const float*)d_in[9];
    float* out = (float*)d_out;   // 32768 x 1024 fp32 (128 MB) — also used as h1/h3 scratch

    // workspace layout (peak ~84 MB):
    //   [0 , 64MB)        hln  (bf16 32768x1024)  -- dead after step 2; region reused:
    //   [0 ,  8MB)        a    (bf16 32768x128)   -- written step 6
    //   [8MB, 72MB)       h2   (bf16 32768x1024)  -- written step 7 (overlaps dead logits tail)
    //   [64MB, 80MB)      logits (fp32 32768x128) -- dead after step 6
    //   [80MB, ...)       softmax stats
    char* ws = (char*)d_ws;
    bf16*  hln    = (bf16*)ws;
    bf16*  a_bf   = (bf16*)ws;
    bf16*  h2     = (bf16*)(ws + 8388608);
    float* logits = (float*)(ws + 67108864);
    float* pm     = (float*)(ws + 83886080);            // 16384 f
    float* psum   = pm + 16384;                         // 16384 f
    float* cm     = psum + 16384;                       // 1024 f
    float* cs     = cm + 1024;                          // 1024 f

    // 1. hln = LayerNorm(x)            (fp32 -> bf16)
    ln_in_kernel<<<dim3(MROWS), dim3(256), 0, stream>>>(x, ln_g, ln_b, hln);
    // 2. h1 = hln @ w_in^T + b_in      -> d_out (fp32)
    gemm_nt<bf16, float, true><<<dim3(MROWS / 64, DIM / 64), dim3(256), 0, stream>>>(
        hln, w_in, b_in, out, MROWS, DIM, DIM);
    // 3. logits = h1 @ w0^T            -> fp32
    gemm_nt<float, float, false><<<dim3(MROWS / 64, KSLOT / 64), dim3(256), 0, stream>>>(
        out, w0, nullptr, logits, MROWS, KSLOT, DIM);
    // 4-5. column softmax stats over N
    smax_part_kernel<<<dim3(KSLOT / 64, 16, BATCH), dim3(64, 4), 0, stream>>>(logits, pm, psum);
    smax_comb_kernel<<<dim3(4), dim3(256), 0, stream>>>(pm, psum, cm, cs);
    // 6. a = softmax / (1e-9 + rowsum_k)  -> bf16 (reuses hln region)
    l1_kernel<<<dim3(MROWS), dim3(128), 0, stream>>>(logits, cm, cs, a_bf);
    // 7. h2 = a @ w1^T                 -> bf16
    gemm_nt<bf16, bf16, false><<<dim3(MROWS / 64, DIM / 64), dim3(256), 0, stream>>>(
        a_bf, w1, nullptr, h2, MROWS, DIM, KSLOT);
    // 8. h3 = h2 @ w_out^T             -> d_out (fp32)
    gemm_nt<bf16, float, false><<<dim3(MROWS / 64, DIM / 64), dim3(256), 0, stream>>>(
        h2, w_out, nullptr, out, MROWS, DIM, DIM);
    // 9. out = relu(LN(h3)*g+b + x)    in-place on d_out
    final_kernel<<<dim3(MROWS), dim3(256), 0, stream>>>(out, x, oln_g, oln_b);
}

// Round 4
// 468.062 us; speedup vs baseline: 4.5942x; 4.5942x over previous
//
#include <hip/hip_runtime.h>
#include <hip/hip_bf16.h>
#include <cstdint>
#include <cstddef>

// Problem constants
#define BATCH 8
#define SEQN 4096
#define DIM 1024
#define KSLOT 128
#define MROWS (BATCH * SEQN)   // 32768
#define LN_EPS 1e-5f

typedef __hip_bfloat16 bf16;
typedef __attribute__((ext_vector_type(8))) short short8;   // 8 bf16 = 4 VGPRs (MFMA A/B frag)
typedef __attribute__((ext_vector_type(4))) float f32x4;    // MFMA C/D frag

// ---------- helpers ----------
__device__ __forceinline__ float bf2f(unsigned short u) {
    return __uint_as_float(((unsigned int)u) << 16);
}
__device__ __forceinline__ unsigned short f2bf(float f) {
    unsigned int u = __float_as_uint(f);
    unsigned int r = (u + 0x7fffu + ((u >> 16) & 1u)) >> 16;  // RNE
    return (unsigned short)r;
}
__device__ __forceinline__ float waveReduceSum(float v) {
    #pragma unroll
    for (int off = 32; off > 0; off >>= 1) v += __shfl_down(v, off, 64);
    return v;
}
__device__ __forceinline__ void load4(const float* p, float* o) {
    float4 v = *reinterpret_cast<const float4*>(p);
    o[0] = v.x; o[1] = v.y; o[2] = v.z; o[3] = v.w;
}
__device__ __forceinline__ void store4(float* p, const float* o) {
    float4 v; v.x = o[0]; v.y = o[1]; v.z = o[2]; v.w = o[3];
    *reinterpret_cast<float4*>(p) = v;
}
__device__ __forceinline__ void store4(bf16* p, const float* o) {
    ushort4 v; v.x = f2bf(o[0]); v.y = f2bf(o[1]); v.z = f2bf(o[2]); v.w = f2bf(o[3]);
    *reinterpret_cast<ushort4*>(p) = v;
}

// async global->LDS, 16 B per lane (global_load_lds_dwordx4)
typedef __attribute__((address_space(1))) const void gvoid;
typedef __attribute__((address_space(3))) void lvoid;
__device__ __forceinline__ void async_cp16(const void* g, void* l) {
    __builtin_amdgcn_global_load_lds((gvoid*)g, (lvoid*)l, 16, 0, 0);
}

// ---------- fp32 SIMT NN GEMM partial (split-K over blockIdx.z=4) ----------
// C_partial[z,k,d] = sum_{e in chunk z} A[k,e] * B[e,d]
// A: Ka x E row-major, B: E x Db row-major. Tile 64x64, BK=16, 4x4 micro.
__global__ __launch_bounds__(256) void nn_partial(
    const float* __restrict__ A, const float* __restrict__ B,
    float* __restrict__ P, int Ka, int E, int Db)
{
    __shared__ float As[16][68];
    __shared__ float Bs[16][68];
    int tid = threadIdx.x, tx = tid & 15, ty = tid >> 4;
    int k0 = blockIdx.x * 64, d0 = blockIdx.y * 64;
    int chunk = E >> 2, e0 = blockIdx.z * chunk;
    int lr = tid >> 2, lk = (tid & 3) * 4;     // A staging: row k0+lr, e off lk
    int er = tid >> 4, dc = (tid & 15) * 4;    // B staging: row e0+et+er, col d0+dc
    float acc[4][4] = {};
    for (int et = 0; et < chunk; et += 16) {
        float av[4], bv[4];
        load4(A + (size_t)(k0 + lr) * E + e0 + et + lk, av);
        load4(B + (size_t)(e0 + et + er) * Db + d0 + dc, bv);
        #pragma unroll
        for (int j = 0; j < 4; j++) { As[lk + j][lr] = av[j]; Bs[er][dc + j] = bv[j]; }
        __syncthreads();
        #pragma unroll
        for (int kk = 0; kk < 16; kk++) {
            float a_[4], b_[4];
            #pragma unroll
            for (int i = 0; i < 4; i++) { a_[i] = As[kk][ty * 4 + i]; b_[i] = Bs[kk][tx * 4 + i]; }
            #pragma unroll
            for (int i = 0; i < 4; i++)
                #pragma unroll
                for (int j = 0; j < 4; j++) acc[i][j] += a_[i] * b_[j];
        }
        __syncthreads();
    }
    float* base = P + ((size_t)blockIdx.z * Ka + k0) * Db + d0;
    #pragma unroll
    for (int i = 0; i < 4; i++) store4(base + (size_t)(ty * 4 + i) * Db + tx * 4, acc[i]);
}

// ---------- reduce 4 partials + split fp32 -> (hi, lo) bf16 ----------
__global__ __launch_bounds__(256) void reduce_split(
    const float* __restrict__ P, bf16* __restrict__ hi, bf16* __restrict__ lo, int n)
{
    int i = (blockIdx.x * 256 + threadIdx.x) * 4;
    if (i >= n) return;
    float s0[4], s1[4], s2[4], s3[4];
    load4(P + i, s0);
    load4(P + (size_t)n + i, s1);
    load4(P + 2 * (size_t)n + i, s2);
    load4(P + 3 * (size_t)n + i, s3);
    ushort4 h, l;
    unsigned short hb[4], lb[4];
    #pragma unroll
    for (int j = 0; j < 4; j++) {
        float s = (s0[j] + s1[j]) + (s2[j] + s3[j]);
        hb[j] = f2bf(s);
        lb[j] = f2bf(s - bf2f(hb[j]));
    }
    h.x = hb[0]; h.y = hb[1]; h.z = hb[2]; h.w = hb[3];
    l.x = lb[0]; l.y = lb[1]; l.z = lb[2]; l.w = lb[3];
    reinterpret_cast<ushort4*>(hi)[i >> 2] = h;
    reinterpret_cast<ushort4*>(lo)[i >> 2] = l;
}

// ---------- bias0[k] = sum_e w0[k,e] * b_in[e] ----------
__global__ __launch_bounds__(64) void bias_comb(
    const float* __restrict__ w0, const float* __restrict__ b_in, float* __restrict__ bias0)
{
    int k = blockIdx.x, lane = threadIdx.x;
    float s = 0.0f;
    for (int e = lane; e < DIM; e += 64) s += w0[(size_t)k * DIM + e] * b_in[e];
    s = waveReduceSum(s);
    if (lane == 0) bias0[k] = s;
}

// ---------- input LayerNorm (fp32 in -> bf16 out) ----------
__global__ __launch_bounds__(256) void ln_in_kernel(
    const float* __restrict__ x, const float* __restrict__ g,
    const float* __restrict__ b, bf16* __restrict__ out)
{
    int r = blockIdx.x;
    int t = threadIdx.x;
    float v[4];
    load4(x + (size_t)r * DIM + t * 4, v);
    float sum = v[0] + v[1] + v[2] + v[3];
    float sq  = v[0]*v[0] + v[1]*v[1] + v[2]*v[2] + v[3]*v[3];
    sum = waveReduceSum(sum);
    sq  = waveReduceSum(sq);
    __shared__ float sA[4], sB[4];
    __shared__ float mean_s, rstd_s;
    int w = t >> 6;
    if ((t & 63) == 0) { sA[w] = sum; sB[w] = sq; }
    __syncthreads();
    if (t == 0) {
        float S = sA[0] + sA[1] + sA[2] + sA[3];
        float Q = sB[0] + sB[1] + sB[2] + sB[3];
        float mean = S * (1.0f / DIM);
        float var = Q * (1.0f / DIM) - mean * mean;
        mean_s = mean;
        rstd_s = rsqrtf(fmaxf(var, 0.0f) + LN_EPS);
    }
    __syncthreads();
    float mean = mean_s, rstd = rstd_s;
    float gv[4], bv[4], o[4];
    load4(g + t * 4, gv);
    load4(b + t * 4, bv);
    #pragma unroll
    for (int j = 0; j < 4; j++) o[j] = (v[j] - mean) * rstd * gv[j] + bv[j];
    store4(out + (size_t)r * DIM + t * 4, o);
}

// ---------- MFMA NT GEMM with hi/lo split weights ----------
// C[m,n] = sum_k A[m,k]*(Whi[n,k]+Wlo[n,k]) (+bias[n]); fp32 out.
// 128x128 tile, BK=32, 256 threads = 4 waves (2x2), 16x16x32 MFMA.
// Both weight halves staged per iter; accumulated into same acc.
template <bool HAS_BIAS>
__global__ __launch_bounds__(256) void gemm_splitB(
    const bf16* __restrict__ A, const bf16* __restrict__ Whi, const bf16* __restrict__ Wlo,
    const float* __restrict__ bias, float* __restrict__ C, int M, int Nout, int Kin)
{
    __shared__ short As[4096];   // 128 rows x 32 k
    __shared__ short Wh[4096];
    __shared__ short Wl[4096];
    const int tid = threadIdx.x, wave = tid >> 6, lane = tid & 63;
    const int wm = wave >> 1, wn = wave & 1;
    const int m0 = blockIdx.x * 128, n0 = blockIdx.y * 128;
    const int srow = tid >> 2, scol = (tid & 3) * 8;
    const bf16* aG0 = A   + (size_t)(m0 + srow) * Kin + scol;
    const bf16* aG1 = aG0 + (size_t)64 * Kin;
    const bf16* hG0 = Whi + (size_t)(n0 + srow) * Kin + scol;
    const bf16* hG1 = hG0 + (size_t)64 * Kin;
    const bf16* lG0 = Wlo + (size_t)(n0 + srow) * Kin + scol;
    const bf16* lG1 = lG0 + (size_t)64 * Kin;
    short* aL0 = As + tid * 8;  short* aL1 = As + 2048 + tid * 8;
    short* hL0 = Wh + tid * 8;  short* hL1 = Wh + 2048 + tid * 8;
    short* lL0 = Wl + tid * 8;  short* lL1 = Wl + 2048 + tid * 8;
    const int fr = lane & 15, kb = (lane >> 4) * 8;

    f32x4 acc[4][4];
    #pragma unroll
    for (int i = 0; i < 4; i++)
        #pragma unroll
        for (int j = 0; j < 4; j++) acc[i][j] = 0.0f;

    for (int kt = 0; kt < Kin; kt += 32) {
        async_cp16(aG0 + kt, aL0);
        async_cp16(aG1 + kt, aL1);
        async_cp16(hG0 + kt, hL0);
        async_cp16(hG1 + kt, hL1);
        async_cp16(lG0 + kt, lL0);
        async_cp16(lG1 + kt, lL1);
        __syncthreads();
        short8 af[4], bh[4], bl[4];
        #pragma unroll
        for (int i = 0; i < 4; i++) {
            af[i] = *(const short8*)(As + (wm * 64 + i * 16 + fr) * 32 + kb);
            bh[i] = *(const short8*)(Wh + (wn * 64 + i * 16 + fr) * 32 + kb);
            bl[i] = *(const short8*)(Wl + (wn * 64 + i * 16 + fr) * 32 + kb);
        }
        #pragma unroll
        for (int i = 0; i < 4; i++)
            #pragma unroll
            for (int j = 0; j < 4; j++) {
                acc[i][j] = __builtin_amdgcn_mfma_f32_16x16x32_bf16(af[i], bh[j], acc[i][j], 0, 0, 0);
                acc[i][j] = __builtin_amdgcn_mfma_f32_16x16x32_bf16(af[i], bl[j], acc[i][j], 0, 0, 0);
            }
        __syncthreads();
    }

    // C/D layout: col=lane&15, row=(lane>>4)*4+reg  [m89/m91 verified]
    const int crow = (lane >> 4) * 4;
    #pragma unroll
    for (int j = 0; j < 4; j++) {
        int col = n0 + wn * 64 + j * 16 + fr;
        float bv = HAS_BIAS ? bias[col] : 0.0f;
        #pragma unroll
        for (int i = 0; i < 4; i++) {
            int rbase = m0 + wm * 64 + i * 16 + crow;
            #pragma unroll
            for (int r = 0; r < 4; r++)
                C[(size_t)(rbase + r) * Nout + col] = acc[i][j][r] + bv;
        }
    }
}

// ---------- softmax over N (axis=1): stage 1, partial online max/sum ----------
__global__ __launch_bounds__(256) void smax_part_kernel(
    const float* __restrict__ logits, float* __restrict__ pm, float* __restrict__ ps)
{
    int kb = blockIdx.x, nb = blockIdx.y, b = blockIdx.z;
    int tx = threadIdx.x, ty = threadIdx.y;
    int k = kb * 64 + tx;
    const float* base = logits + ((size_t)b * SEQN) * KSLOT + k;
    int n0 = nb * 256 + ty * 64;
    float m = -1e30f, s = 0.0f;
    for (int j = 0; j < 64; j++) {
        float v = base[(size_t)(n0 + j) * KSLOT];
        if (v > m) { s = s * __expf(m - v) + 1.0f; m = v; }
        else       { s += __expf(v - m); }
    }
    __shared__ float lm[4][64], ls[4][64];
    lm[ty][tx] = m; ls[ty][tx] = s;
    __syncthreads();
    if (ty == 0) {
        #pragma unroll
        for (int q = 1; q < 4; q++) {
            float m2 = lm[q][tx], s2 = ls[q][tx];
            float nm = fmaxf(m, m2);
            s = s * __expf(m - nm) + s2 * __expf(m2 - nm);
            m = nm;
        }
        int col = b * KSLOT + k;
        pm[col * 16 + nb] = m;
        ps[col * 16 + nb] = s;
    }
}

__global__ __launch_bounds__(256) void smax_comb_kernel(
    const float* __restrict__ pm, const float* __restrict__ ps,
    float* __restrict__ cm, float* __restrict__ cs)
{
    int c = blockIdx.x * 256 + threadIdx.x;  // 0..1023 = b*K+k
    float m = -1e30f, s = 0.0f;
    #pragma unroll
    for (int nb = 0; nb < 16; nb++) {
        float m2 = pm[c * 16 + nb], s2 = ps[c * 16 + nb];
        float nm = fmaxf(m, m2);
        s = s * __expf(m - nm) + s2 * __expf(m2 - nm);
        m = nm;
    }
    cm[c] = m;
    cs[c] = s;
}

// ---------- softmax apply + L1 norm over K -> bf16 a ----------
__global__ __launch_bounds__(128) void l1_kernel(
    const float* __restrict__ logits, const float* __restrict__ cm,
    const float* __restrict__ cs, bf16* __restrict__ aout)
{
    int r = blockIdx.x;
    int b = r >> 12;            // r / SEQN
    int k = threadIdx.x;
    int col = b * KSLOT + k;
    float e = __expf(logits[(size_t)r * KSLOT + k] - cm[col]) / cs[col];
    float t = waveReduceSum(e);
    __shared__ float sh[2];
    __shared__ float tot_s;
    if ((k & 63) == 0) sh[k >> 6] = t;
    __syncthreads();
    if (k == 0) tot_s = sh[0] + sh[1];
    __syncthreads();
    float o = e / (1e-9f + tot_s);
    ((unsigned short*)aout)[(size_t)r * KSLOT + k] = f2bf(o);
}

// ---------- final: out = relu(LN(h3)*g+b + x), in-place fp32 on h ----------
__global__ __launch_bounds__(256) void final_kernel(
    float* __restrict__ h, const float* __restrict__ x,
    const float* __restrict__ g, const float* __restrict__ b)
{
    int r = blockIdx.x;
    int t = threadIdx.x;
    float v[4];
    load4(h + (size_t)r * DIM + t * 4, v);
    float sum = v[0] + v[1] + v[2] + v[3];
    float sq  = v[0]*v[0] + v[1]*v[1] + v[2]*v[2] + v[3]*v[3];
    sum = waveReduceSum(sum);
    sq  = waveReduceSum(sq);
    __shared__ float sA[4], sB[4];
    __shared__ float mean_s, rstd_s;
    int w = t >> 6;
    if ((t & 63) == 0) { sA[w] = sum; sB[w] = sq; }
    __syncthreads();
    if (t == 0) {
        float S = sA[0] + sA[1] + sA[2] + sA[3];
        float Q = sB[0] + sB[1] + sB[2] + sB[3];
        float mean = S * (1.0f / DIM);
        float var = Q * (1.0f / DIM) - mean * mean;
        mean_s = mean;
        rstd_s = rsqrtf(fmaxf(var, 0.0f) + LN_EPS);
    }
    __syncthreads();
    float mean = mean_s, rstd = rstd_s;
    float gv[4], bv[4], xv[4], o[4];
    load4(g + t * 4, gv);
    load4(b + t * 4, bv);
    load4(x + (size_t)r * DIM + t * 4, xv);
    #pragma unroll
    for (int j = 0; j < 4; j++) {
        float z = (v[j] - mean) * rstd * gv[j] + bv[j] + xv[j];
        o[j] = fmaxf(z, 0.0f);
    }
    store4(h + (size_t)r * DIM + t * 4, o);
}

extern "C" void kernel_launch(void* const* d_in, const int* in_sizes, int n_in,
                              void* d_out, int out_size, void* d_ws, size_t ws_size,
                              hipStream_t stream)
{
    const float* x     = (const float*)d_in[0];
    const float* ln_g  = (const float*)d_in[1];
    const float* ln_b  = (const float*)d_in[2];
    const float* w_in  = (const float*)d_in[3];
    const float* b_in  = (const float*)d_in[4];
    const float* w0    = (const float*)d_in[5];
    const float* w1    = (const float*)d_in[6];
    const float* w_out = (const float*)d_in[7];
    const float* oln_g = (const float*)d_in[8];
    const float* oln_b = (const float*)d_in[9];
    float* out = (float*)d_out;   // 32768x1024 fp32; h3 written here, then final in-place

    // ws layout (peak 81.2 MiB, < 84 MiB proven safe):
    //   [0, 64 MiB)        hln bf16   (dead after logits GEMM) -> a bf16 reuses [0, 8 MiB)
    //   [64, 80 MiB)       partials P1 [64,66) + P2 [66,68) (dead after reduce)
    //                      then logits fp32 (whole region)
    //   [80 MiB, ...)      wc_hi/wc_lo/wc2_hi/wc2_lo/bias0/softmax stats
    char* ws = (char*)d_ws;
    bf16*  hln    = (bf16*)ws;
    bf16*  a_bf   = (bf16*)ws;
    float* logits = (float*)(ws + 67108864);
    float* P1     = (float*)(ws + 67108864);            // 4x128x1024 fp32 = 2 MiB
    float* P2     = (float*)(ws + 69206016);            // 4x1024x128 fp32 = 2 MiB
    bf16*  wc_hi  = (bf16*)(ws + 83886080);             // 128x1024
    bf16*  wc_lo  = (bf16*)(ws + 84148224);
    bf16*  wc2_hi = (bf16*)(ws + 84410368);             // 1024x128
    bf16*  wc2_lo = (bf16*)(ws + 84672512);
    float* bias0  = (float*)(ws + 84934656);            // 128 f
    float* pm     = (float*)(ws + 84935168);            // 16384 f
    float* psum   = (float*)(ws + 85000704);            // 16384 f
    float* cm     = (float*)(ws + 85066240);            // 1024 f
    float* cs     = (float*)(ws + 85070336);            // 1024 f

    // 0a. w_comb = w0 @ w_in   (128x1024, contraction over e=1024), fp32 split-K
    nn_partial<<<dim3(2, 16, 4), dim3(256), 0, stream>>>(w0, w_in, P1, KSLOT, DIM, DIM);
    // 0b. w_comb2 = w_out @ w1 (1024x128, contraction over d=1024), fp32 split-K
    nn_partial<<<dim3(16, 2, 4), dim3(256), 0, stream>>>(w_out, w1, P2, DIM, DIM, KSLOT);
    // 0c. reduce partials, split into hi/lo bf16 pairs
    reduce_split<<<dim3(128), dim3(256), 0, stream>>>(P1, wc_hi, wc_lo, KSLOT * DIM);
    reduce_split<<<dim3(128), dim3(256), 0, stream>>>(P2, wc2_hi, wc2_lo, DIM * KSLOT);
    // 0d. bias0 = w0 @ b_in
    bias_comb<<<dim3(KSLOT), dim3(64), 0, stream>>>(w0, b_in, bias0);
    // 1. hln = LayerNorm(x)  (fp32 -> bf16)
    ln_in_kernel<<<dim3(MROWS), dim3(256), 0, stream>>>(x, ln_g, ln_b, hln);
    // 2. logits = hln @ w_comb^T + bias0   (MFMA, split weights, fp32 out)
    gemm_splitB<true><<<dim3(MROWS / 128, KSLOT / 128), dim3(256), 0, stream>>>(
        hln, wc_hi, wc_lo, bias0, logits, MROWS, KSLOT, DIM);
    // 3-4. column softmax stats over N
    smax_part_kernel<<<dim3(KSLOT / 64, 16, BATCH), dim3(64, 4), 0, stream>>>(logits, pm, psum);
    smax_comb_kernel<<<dim3(4), dim3(256), 0, stream>>>(pm, psum, cm, cs);
    // 5. a = softmax / (1e-9 + rowsum_k) -> bf16 (reuses dead hln region)
    l1_kernel<<<dim3(MROWS), dim3(128), 0, stream>>>(logits, cm, cs, a_bf);
    // 6. h3 = a @ w_comb2^T  (MFMA, split weights) -> d_out fp32
    gemm_splitB<false><<<dim3(MROWS / 128, DIM / 128), dim3(256), 0, stream>>>(
        a_bf, wc2_hi, wc2_lo, nullptr, out, MROWS, DIM, KSLOT);
    // 7. out = relu(LN(h3)*g+b + x)  in-place on d_out
    final_kernel<<<dim3(MROWS), dim3(256), 0, stream>>>(out, x, oln_g, oln_b);
}

// Round 5
// 412.345 us; speedup vs baseline: 5.2150x; 1.1351x over previous
//
#include <hip/hip_runtime.h>
#include <hip/hip_bf16.h>
#include <cstdint>
#include <cstddef>

// Problem constants
#define BATCH 8
#define SEQN 4096
#define DIM 1024
#define KSLOT 128
#define MROWS (BATCH * SEQN)   // 32768
#define LN_EPS 1e-5f

typedef __hip_bfloat16 bf16;
typedef __attribute__((ext_vector_type(8))) short short8;   // 8 bf16 = 4 VGPRs (MFMA A/B frag)
typedef __attribute__((ext_vector_type(4))) float f32x4;    // MFMA C/D frag

// ---------- helpers ----------
__device__ __forceinline__ float bf2f(unsigned short u) {
    return __uint_as_float(((unsigned int)u) << 16);
}
__device__ __forceinline__ unsigned short f2bf(float f) {
    unsigned int u = __float_as_uint(f);
    unsigned int r = (u + 0x7fffu + ((u >> 16) & 1u)) >> 16;  // RNE
    return (unsigned short)r;
}
__device__ __forceinline__ float waveReduceSum(float v) {
    #pragma unroll
    for (int off = 32; off > 0; off >>= 1) v += __shfl_down(v, off, 64);
    return v;
}
__device__ __forceinline__ void load4(const float* p, float* o) {
    float4 v = *reinterpret_cast<const float4*>(p);
    o[0] = v.x; o[1] = v.y; o[2] = v.z; o[3] = v.w;
}
__device__ __forceinline__ void load4(const bf16* p, float* o) {
    ushort4 v = *reinterpret_cast<const ushort4*>(p);
    o[0] = bf2f(v.x); o[1] = bf2f(v.y); o[2] = bf2f(v.z); o[3] = bf2f(v.w);
}
__device__ __forceinline__ void store4(float* p, const float* o) {
    float4 v; v.x = o[0]; v.y = o[1]; v.z = o[2]; v.w = o[3];
    *reinterpret_cast<float4*>(p) = v;
}
__device__ __forceinline__ void store4(bf16* p, const float* o) {
    ushort4 v; v.x = f2bf(o[0]); v.y = f2bf(o[1]); v.z = f2bf(o[2]); v.w = f2bf(o[3]);
    *reinterpret_cast<ushort4*>(p) = v;
}

// async global->LDS, 16 B per lane (global_load_lds_dwordx4)
typedef __attribute__((address_space(1))) const void gvoid;
typedef __attribute__((address_space(3))) void lvoid;
__device__ __forceinline__ void async_cp16(const void* g, void* l) {
    __builtin_amdgcn_global_load_lds((gvoid*)g, (lvoid*)l, 16, 0, 0);
}

// ---------- fp32 SIMT NN GEMM partial (split-K over blockIdx.z=8) ----------
// P[z,k,d] = sum_{e in chunk z} A[k,e] * B[e,d]
__global__ __launch_bounds__(256) void nn_partial(
    const float* __restrict__ A, const float* __restrict__ B,
    float* __restrict__ P, int Ka, int E, int Db)
{
    __shared__ float As[16][68];
    __shared__ float Bs[16][68];
    int tid = threadIdx.x, tx = tid & 15, ty = tid >> 4;
    int k0 = blockIdx.x * 64, d0 = blockIdx.y * 64;
    int chunk = E >> 3, e0 = blockIdx.z * chunk;
    int lr = tid >> 2, lk = (tid & 3) * 4;     // A staging: row k0+lr, e off lk
    int er = tid >> 4, dc = (tid & 15) * 4;    // B staging: row e0+et+er, col d0+dc
    float acc[4][4] = {};
    for (int et = 0; et < chunk; et += 16) {
        float av[4], bv[4];
        load4(A + (size_t)(k0 + lr) * E + e0 + et + lk, av);
        load4(B + (size_t)(e0 + et + er) * Db + d0 + dc, bv);
        #pragma unroll
        for (int j = 0; j < 4; j++) { As[lk + j][lr] = av[j]; Bs[er][dc + j] = bv[j]; }
        __syncthreads();
        #pragma unroll
        for (int kk = 0; kk < 16; kk++) {
            float a_[4], b_[4];
            #pragma unroll
            for (int i = 0; i < 4; i++) { a_[i] = As[kk][ty * 4 + i]; b_[i] = Bs[kk][tx * 4 + i]; }
            #pragma unroll
            for (int i = 0; i < 4; i++)
                #pragma unroll
                for (int j = 0; j < 4; j++) acc[i][j] += a_[i] * b_[j];
        }
        __syncthreads();
    }
    float* base = P + ((size_t)blockIdx.z * Ka + k0) * Db + d0;
    #pragma unroll
    for (int i = 0; i < 4; i++) store4(base + (size_t)(ty * 4 + i) * Db + tx * 4, acc[i]);
}

// ---------- reduce 8 partials + split fp32 -> (hi, lo) bf16; both matrices ----------
__global__ __launch_bounds__(256) void reduce_split8(
    const float* __restrict__ P1, const float* __restrict__ P2,
    bf16* __restrict__ hi1, bf16* __restrict__ lo1,
    bf16* __restrict__ hi2, bf16* __restrict__ lo2, int n)
{
    int bid = blockIdx.x;
    const float* P; bf16 *hi, *lo; int base;
    if (bid < 128) { P = P1; hi = hi1; lo = lo1; base = bid; }
    else           { P = P2; hi = hi2; lo = lo2; base = bid - 128; }
    int i = (base * 256 + threadIdx.x) * 4;
    if (i >= n) return;
    float s[4] = {0.f, 0.f, 0.f, 0.f};
    #pragma unroll
    for (int z = 0; z < 8; z++) {
        float t[4];
        load4(P + (size_t)z * n + i, t);
        #pragma unroll
        for (int j = 0; j < 4; j++) s[j] += t[j];
    }
    ushort4 h, l;
    unsigned short hb[4], lb[4];
    #pragma unroll
    for (int j = 0; j < 4; j++) {
        hb[j] = f2bf(s[j]);
        lb[j] = f2bf(s[j] - bf2f(hb[j]));
    }
    h.x = hb[0]; h.y = hb[1]; h.z = hb[2]; h.w = hb[3];
    l.x = lb[0]; l.y = lb[1]; l.z = lb[2]; l.w = lb[3];
    reinterpret_cast<ushort4*>(hi)[i >> 2] = h;
    reinterpret_cast<ushort4*>(lo)[i >> 2] = l;
}

// ---------- bias0[k] = sum_e w0[k,e] * b_in[e] ----------
__global__ __launch_bounds__(64) void bias_comb(
    const float* __restrict__ w0, const float* __restrict__ b_in, float* __restrict__ bias0)
{
    int k = blockIdx.x, lane = threadIdx.x;
    float s = 0.0f;
    for (int e = lane; e < DIM; e += 64) s += w0[(size_t)k * DIM + e] * b_in[e];
    s = waveReduceSum(s);
    if (lane == 0) bias0[k] = s;
}

// ---------- input LayerNorm (fp32 in -> bf16 out) ----------
__global__ __launch_bounds__(256) void ln_in_kernel(
    const float* __restrict__ x, const float* __restrict__ g,
    const float* __restrict__ b, bf16* __restrict__ out)
{
    int r = blockIdx.x;
    int t = threadIdx.x;
    float v[4];
    load4(x + (size_t)r * DIM + t * 4, v);
    float sum = v[0] + v[1] + v[2] + v[3];
    float sq  = v[0]*v[0] + v[1]*v[1] + v[2]*v[2] + v[3]*v[3];
    sum = waveReduceSum(sum);
    sq  = waveReduceSum(sq);
    __shared__ float sA[4], sB[4];
    __shared__ float mean_s, rstd_s;
    int w = t >> 6;
    if ((t & 63) == 0) { sA[w] = sum; sB[w] = sq; }
    __syncthreads();
    if (t == 0) {
        float S = sA[0] + sA[1] + sA[2] + sA[3];
        float Q = sB[0] + sB[1] + sB[2] + sB[3];
        float mean = S * (1.0f / DIM);
        float var = Q * (1.0f / DIM) - mean * mean;
        mean_s = mean;
        rstd_s = rsqrtf(fmaxf(var, 0.0f) + LN_EPS);
    }
    __syncthreads();
    float mean = mean_s, rstd = rstd_s;
    float gv[4], bv[4], o[4];
    load4(g + t * 4, gv);
    load4(b + t * 4, bv);
    #pragma unroll
    for (int j = 0; j < 4; j++) o[j] = (v[j] - mean) * rstd * gv[j] + bv[j];
    store4(out + (size_t)r * DIM + t * 4, o);
}

// ---------- logits GEMM: 64x128 tile, split-B hi/lo, fp32 out ----------
// logits[m, k] = sum_d hln[m,d] * (Whi[k,d]+Wlo[k,d]) + bias0[k]
// Nout = KSLOT = 128 (whole width per block); grid (M/64) = 512 -> 2 blocks/CU.
__global__ __launch_bounds__(256) void gemm_logits(
    const bf16* __restrict__ A, const bf16* __restrict__ Whi, const bf16* __restrict__ Wlo,
    const float* __restrict__ bias, float* __restrict__ C, int M, int Kin)
{
    __shared__ short As[64 * 32];    // 4 KB
    __shared__ short Wh[128 * 32];   // 8 KB
    __shared__ short Wl[128 * 32];   // 8 KB
    const int tid = threadIdx.x, wave = tid >> 6, lane = tid & 63;
    const int wm = wave >> 1, wn = wave & 1;           // wave: 32 rows x 64 cols
    const int m0 = blockIdx.x * 64;
    const int srow = tid >> 2, scol = (tid & 3) * 8;
    const bf16* aG  = A   + (size_t)(m0 + srow) * Kin + scol;
    const bf16* hG0 = Whi + (size_t)srow * Kin + scol;
    const bf16* hG1 = hG0 + (size_t)64 * Kin;
    const bf16* lG0 = Wlo + (size_t)srow * Kin + scol;
    const bf16* lG1 = lG0 + (size_t)64 * Kin;
    short* aL  = As + tid * 8;
    short* hL0 = Wh + tid * 8;  short* hL1 = Wh + 2048 + tid * 8;
    short* lL0 = Wl + tid * 8;  short* lL1 = Wl + 2048 + tid * 8;
    const int fr = lane & 15, kb = (lane >> 4) * 8;

    f32x4 acc[2][4];
    #pragma unroll
    for (int i = 0; i < 2; i++)
        #pragma unroll
        for (int j = 0; j < 4; j++) acc[i][j] = 0.0f;

    for (int kt = 0; kt < Kin; kt += 32) {
        async_cp16(aG + kt, aL);
        async_cp16(hG0 + kt, hL0);
        async_cp16(hG1 + kt, hL1);
        async_cp16(lG0 + kt, lL0);
        async_cp16(lG1 + kt, lL1);
        __syncthreads();
        short8 af[2], bh[4], bl[4];
        #pragma unroll
        for (int i = 0; i < 2; i++)
            af[i] = *(const short8*)(As + (wm * 32 + i * 16 + fr) * 32 + kb);
        #pragma unroll
        for (int j = 0; j < 4; j++) {
            bh[j] = *(const short8*)(Wh + (wn * 64 + j * 16 + fr) * 32 + kb);
            bl[j] = *(const short8*)(Wl + (wn * 64 + j * 16 + fr) * 32 + kb);
        }
        #pragma unroll
        for (int i = 0; i < 2; i++)
            #pragma unroll
            for (int j = 0; j < 4; j++) {
                acc[i][j] = __builtin_amdgcn_mfma_f32_16x16x32_bf16(af[i], bh[j], acc[i][j], 0, 0, 0);
                acc[i][j] = __builtin_amdgcn_mfma_f32_16x16x32_bf16(af[i], bl[j], acc[i][j], 0, 0, 0);
            }
        __syncthreads();
    }

    const int crow = (lane >> 4) * 4;   // C/D: col=lane&15, row=(lane>>4)*4+reg
    #pragma unroll
    for (int j = 0; j < 4; j++) {
        int col = wn * 64 + j * 16 + fr;
        float bv = bias[col];
        #pragma unroll
        for (int i = 0; i < 2; i++) {
            int rbase = m0 + wm * 32 + i * 16 + crow;
            #pragma unroll
            for (int r = 0; r < 4; r++)
                C[(size_t)(rbase + r) * KSLOT + col] = acc[i][j][r] + bv;
        }
    }
}

// ---------- h3 GEMM: 128x128 tile, split-B hi/lo, bf16 out ----------
// h3[m,d] = sum_k a[m,k] * (W2hi[d,k]+W2lo[d,k]);  Kin = KSLOT = 128 (4 iters)
__global__ __launch_bounds__(256) void gemm_h3(
    const bf16* __restrict__ A, const bf16* __restrict__ Whi, const bf16* __restrict__ Wlo,
    bf16* __restrict__ C, int M, int Nout, int Kin)
{
    __shared__ short As[4096];
    __shared__ short Wh[4096];
    __shared__ short Wl[4096];
    const int tid = threadIdx.x, wave = tid >> 6, lane = tid & 63;
    const int wm = wave >> 1, wn = wave & 1;
    const int m0 = blockIdx.x * 128, n0 = blockIdx.y * 128;
    const int srow = tid >> 2, scol = (tid & 3) * 8;
    const bf16* aG0 = A   + (size_t)(m0 + srow) * Kin + scol;
    const bf16* aG1 = aG0 + (size_t)64 * Kin;
    const bf16* hG0 = Whi + (size_t)(n0 + srow) * Kin + scol;
    const bf16* hG1 = hG0 + (size_t)64 * Kin;
    const bf16* lG0 = Wlo + (size_t)(n0 + srow) * Kin + scol;
    const bf16* lG1 = lG0 + (size_t)64 * Kin;
    short* aL0 = As + tid * 8;  short* aL1 = As + 2048 + tid * 8;
    short* hL0 = Wh + tid * 8;  short* hL1 = Wh + 2048 + tid * 8;
    short* lL0 = Wl + tid * 8;  short* lL1 = Wl + 2048 + tid * 8;
    const int fr = lane & 15, kb = (lane >> 4) * 8;

    f32x4 acc[4][4];
    #pragma unroll
    for (int i = 0; i < 4; i++)
        #pragma unroll
        for (int j = 0; j < 4; j++) acc[i][j] = 0.0f;

    for (int kt = 0; kt < Kin; kt += 32) {
        async_cp16(aG0 + kt, aL0);
        async_cp16(aG1 + kt, aL1);
        async_cp16(hG0 + kt, hL0);
        async_cp16(hG1 + kt, hL1);
        async_cp16(lG0 + kt, lL0);
        async_cp16(lG1 + kt, lL1);
        __syncthreads();
        short8 af[4], bh[4], bl[4];
        #pragma unroll
        for (int i = 0; i < 4; i++) {
            af[i] = *(const short8*)(As + (wm * 64 + i * 16 + fr) * 32 + kb);
            bh[i] = *(const short8*)(Wh + (wn * 64 + i * 16 + fr) * 32 + kb);
            bl[i] = *(const short8*)(Wl + (wn * 64 + i * 16 + fr) * 32 + kb);
        }
        #pragma unroll
        for (int i = 0; i < 4; i++)
            #pragma unroll
            for (int j = 0; j < 4; j++) {
                acc[i][j] = __builtin_amdgcn_mfma_f32_16x16x32_bf16(af[i], bh[j], acc[i][j], 0, 0, 0);
                acc[i][j] = __builtin_amdgcn_mfma_f32_16x16x32_bf16(af[i], bl[j], acc[i][j], 0, 0, 0);
            }
        __syncthreads();
    }

    const int crow = (lane >> 4) * 4;   // C/D: col=lane&15, row=(lane>>4)*4+reg
    #pragma unroll
    for (int j = 0; j < 4; j++) {
        int col = n0 + wn * 64 + j * 16 + fr;
        #pragma unroll
        for (int i = 0; i < 4; i++) {
            int rbase = m0 + wm * 64 + i * 16 + crow;
            #pragma unroll
            for (int r = 0; r < 4; r++)
                *(unsigned short*)(C + (size_t)(rbase + r) * Nout + col) = f2bf(acc[i][j][r]);
        }
    }
}

// ---------- softmax over N (axis=1): stage 1, partial online max/sum ----------
__global__ __launch_bounds__(256) void smax_part_kernel(
    const float* __restrict__ logits, float* __restrict__ pm, float* __restrict__ ps)
{
    int kb = blockIdx.x, nb = blockIdx.y, b = blockIdx.z;
    int tx = threadIdx.x, ty = threadIdx.y;
    int k = kb * 64 + tx;
    const float* base = logits + ((size_t)b * SEQN) * KSLOT + k;
    int n0 = nb * 256 + ty * 64;
    float m = -1e30f, s = 0.0f;
    for (int j = 0; j < 64; j++) {
        float v = base[(size_t)(n0 + j) * KSLOT];
        if (v > m) { s = s * __expf(m - v) + 1.0f; m = v; }
        else       { s += __expf(v - m); }
    }
    __shared__ float lm[4][64], ls[4][64];
    lm[ty][tx] = m; ls[ty][tx] = s;
    __syncthreads();
    if (ty == 0) {
        #pragma unroll
        for (int q = 1; q < 4; q++) {
            float m2 = lm[q][tx], s2 = ls[q][tx];
            float nm = fmaxf(m, m2);
            s = s * __expf(m - nm) + s2 * __expf(m2 - nm);
            m = nm;
        }
        int col = b * KSLOT + k;
        pm[col * 16 + nb] = m;
        ps[col * 16 + nb] = s;
    }
}

__global__ __launch_bounds__(256) void smax_comb_kernel(
    const float* __restrict__ pm, const float* __restrict__ ps,
    float* __restrict__ cm, float* __restrict__ cs)
{
    int c = blockIdx.x * 256 + threadIdx.x;  // 0..1023 = b*K+k
    float m = -1e30f, s = 0.0f;
    #pragma unroll
    for (int nb = 0; nb < 16; nb++) {
        float m2 = pm[c * 16 + nb], s2 = ps[c * 16 + nb];
        float nm = fmaxf(m, m2);
        s = s * __expf(m - nm) + s2 * __expf(m2 - nm);
        m = nm;
    }
    cm[c] = m;
    cs[c] = s;
}

// ---------- softmax apply + L1 norm over K -> bf16 a ----------
__global__ __launch_bounds__(128) void l1_kernel(
    const float* __restrict__ logits, const float* __restrict__ cm,
    const float* __restrict__ cs, bf16* __restrict__ aout)
{
    int r = blockIdx.x;
    int b = r >> 12;            // r / SEQN
    int k = threadIdx.x;
    int col = b * KSLOT + k;
    float e = __expf(logits[(size_t)r * KSLOT + k] - cm[col]) / cs[col];
    float t = waveReduceSum(e);
    __shared__ float sh[2];
    __shared__ float tot_s;
    if ((k & 63) == 0) sh[k >> 6] = t;
    __syncthreads();
    if (k == 0) tot_s = sh[0] + sh[1];
    __syncthreads();
    float o = e / (1e-9f + tot_s);
    ((unsigned short*)aout)[(size_t)r * KSLOT + k] = f2bf(o);
}

// ---------- final: out = relu(LN(h3)*g+b + x); h3 bf16 in, fp32 out ----------
__global__ __launch_bounds__(256) void final_kernel(
    const bf16* __restrict__ h, const float* __restrict__ x,
    const float* __restrict__ g, const float* __restrict__ b, float* __restrict__ out)
{
    int r = blockIdx.x;
    int t = threadIdx.x;
    float v[4];
    load4(h + (size_t)r * DIM + t * 4, v);
    float sum = v[0] + v[1] + v[2] + v[3];
    float sq  = v[0]*v[0] + v[1]*v[1] + v[2]*v[2] + v[3]*v[3];
    sum = waveReduceSum(sum);
    sq  = waveReduceSum(sq);
    __shared__ float sA[4], sB[4];
    __shared__ float mean_s, rstd_s;
    int w = t >> 6;
    if ((t & 63) == 0) { sA[w] = sum; sB[w] = sq; }
    __syncthreads();
    if (t == 0) {
        float S = sA[0] + sA[1] + sA[2] + sA[3];
        float Q = sB[0] + sB[1] + sB[2] + sB[3];
        float mean = S * (1.0f / DIM);
        float var = Q * (1.0f / DIM) - mean * mean;
        mean_s = mean;
        rstd_s = rsqrtf(fmaxf(var, 0.0f) + LN_EPS);
    }
    __syncthreads();
    float mean = mean_s, rstd = rstd_s;
    float gv[4], bv[4], xv[4], o[4];
    load4(g + t * 4, gv);
    load4(b + t * 4, bv);
    load4(x + (size_t)r * DIM + t * 4, xv);
    #pragma unroll
    for (int j = 0; j < 4; j++) {
        float z = (v[j] - mean) * rstd * gv[j] + bv[j] + xv[j];
        o[j] = fmaxf(z, 0.0f);
    }
    store4(out + (size_t)r * DIM + t * 4, o);
}

extern "C" void kernel_launch(void* const* d_in, const int* in_sizes, int n_in,
                              void* d_out, int out_size, void* d_ws, size_t ws_size,
                              hipStream_t stream)
{
    const float* x     = (const float*)d_in[0];
    const float* ln_g  = (const float*)d_in[1];
    const float* ln_b  = (const float*)d_in[2];
    const float* w_in  = (const float*)d_in[3];
    const float* b_in  = (const float*)d_in[4];
    const float* w0    = (const float*)d_in[5];
    const float* w1    = (const float*)d_in[6];
    const float* w_out = (const float*)d_in[7];
    const float* oln_g = (const float*)d_in[8];
    const float* oln_b = (const float*)d_in[9];
    float* out = (float*)d_out;   // final fp32 output only

    // ws layout (peak ~81.2 MiB):
    //   [0, 64 MiB)   hln bf16 (dead after logits GEMM); a bf16 reuses [0, 8 MiB)
    //   [8, 72 MiB)   h3b bf16 (written by gemm_h3 after logits/hln dead)
    //   [64, 80 MiB)  P1 [64,68) + P2 [68,72) (dead after reduce), then logits fp32
    //   [80 MiB, ..)  wc_hi/wc_lo/wc2_hi/wc2_lo/bias0/softmax stats
    char* ws = (char*)d_ws;
    bf16*  hln    = (bf16*)ws;
    bf16*  a_bf   = (bf16*)ws;
    bf16*  h3b    = (bf16*)(ws + 8388608);
    float* logits = (float*)(ws + 67108864);
    float* P1     = (float*)(ws + 67108864);            // 8x128x1024 fp32 = 4 MiB
    float* P2     = (float*)(ws + 71303168);            // 8x1024x128 fp32 = 4 MiB
    bf16*  wc_hi  = (bf16*)(ws + 83886080);             // 128x1024
    bf16*  wc_lo  = (bf16*)(ws + 84148224);
    bf16*  wc2_hi = (bf16*)(ws + 84410368);             // 1024x128
    bf16*  wc2_lo = (bf16*)(ws + 84672512);
    float* bias0  = (float*)(ws + 84934656);            // 128 f
    float* pm     = (float*)(ws + 84935168);            // 16384 f
    float* psum   = (float*)(ws + 85000704);            // 16384 f
    float* cm     = (float*)(ws + 85066240);            // 1024 f
    float* cs     = (float*)(ws + 85070336);            // 1024 f

    // 0a. w_comb = w0 @ w_in   (128x1024), split-K 8
    nn_partial<<<dim3(2, 16, 8), dim3(256), 0, stream>>>(w0, w_in, P1, KSLOT, DIM, DIM);
    // 0b. w_comb2 = w_out @ w1 (1024x128), split-K 8
    nn_partial<<<dim3(16, 2, 8), dim3(256), 0, stream>>>(w_out, w1, P2, DIM, DIM, KSLOT);
    // 0c. reduce partials + split hi/lo (both matrices, one launch)
    reduce_split8<<<dim3(256), dim3(256), 0, stream>>>(P1, P2, wc_hi, wc_lo, wc2_hi, wc2_lo, KSLOT * DIM);
    // 0d. bias0 = w0 @ b_in
    bias_comb<<<dim3(KSLOT), dim3(64), 0, stream>>>(w0, b_in, bias0);
    // 1. hln = LayerNorm(x)  (fp32 -> bf16)
    ln_in_kernel<<<dim3(MROWS), dim3(256), 0, stream>>>(x, ln_g, ln_b, hln);
    // 2. logits = hln @ w_comb^T + bias0   (64x128 tiles, 2 blocks/CU)
    gemm_logits<<<dim3(MROWS / 64), dim3(256), 0, stream>>>(
        hln, wc_hi, wc_lo, bias0, logits, MROWS, DIM);
    // 3-4. column softmax stats over N
    smax_part_kernel<<<dim3(KSLOT / 64, 16, BATCH), dim3(64, 4), 0, stream>>>(logits, pm, psum);
    smax_comb_kernel<<<dim3(4), dim3(256), 0, stream>>>(pm, psum, cm, cs);
    // 5. a = softmax / (1e-9 + rowsum_k) -> bf16 (reuses dead hln region)
    l1_kernel<<<dim3(MROWS), dim3(128), 0, stream>>>(logits, cm, cs, a_bf);
    // 6. h3 = a @ w_comb2^T -> bf16 (ws mid region; logits dead after step 5)
    gemm_h3<<<dim3(MROWS / 128, DIM / 128), dim3(256), 0, stream>>>(
        a_bf, wc2_hi, wc2_lo, h3b, MROWS, DIM, KSLOT);
    // 7. out = relu(LN(h3)*g+b + x) -> d_out fp32
    final_kernel<<<dim3(MROWS), dim3(256), 0, stream>>>(h3b, x, oln_g, oln_b, out);
}